// Round 1
// baseline (105.494 us; speedup 1.0000x reference)
//
#include <hip/hip_runtime.h>
#include <float.h>

#define D_DIM 1024
#define T_DIM 1024
#define B_DIM 16
#define NTOP 5
#define RAD 32           // exp(-k^2/8) == 0.0f in fp32 for |k| >= 29; 32 is safely exact
#define NORM_C 0.19947114f  // np.float32(1/(2*sqrt(2*pi)))

// Stage 1: per (b2,t) row of 1024 floats, find top-5 indices (jax tie-break:
// lower index wins on equal values). One wave (64 lanes) per row.
__global__ __launch_bounds__(256) void topk5_kernel(const float* __restrict__ in,
                                                    int* __restrict__ idx_out) {
    const int row  = (blockIdx.x * blockDim.x + threadIdx.x) >> 6;  // 0..16383
    const int lane = threadIdx.x & 63;

    const float4* row4 = (const float4*)(in + (size_t)row * D_DIM);

    float vals[16];
    int   eidx[16];
#pragma unroll
    for (int j = 0; j < 4; ++j) {
        float4 v = row4[lane + 64 * j];        // consecutive lanes -> consecutive 16B: coalesced
        int base = 4 * (lane + 64 * j);
        vals[4 * j + 0] = v.x; eidx[4 * j + 0] = base + 0;
        vals[4 * j + 1] = v.y; eidx[4 * j + 1] = base + 1;
        vals[4 * j + 2] = v.z; eidx[4 * j + 2] = base + 2;
        vals[4 * j + 3] = v.w; eidx[4 * j + 3] = base + 3;
    }

    int chosen[NTOP];
#pragma unroll
    for (int it = 0; it < NTOP; ++it) {
        // lane-local argmax (strict > keeps lowest index; eidx[k] increases with k)
        float bv = -FLT_MAX;
        int   bi = 0x7fffffff;
#pragma unroll
        for (int k = 0; k < 16; ++k) {
            if (vals[k] > bv) { bv = vals[k]; bi = eidx[k]; }
        }
        // 64-lane butterfly argmax, tie -> lower index
#pragma unroll
        for (int s = 1; s < 64; s <<= 1) {
            float ov = __shfl_xor(bv, s);
            int   oi = __shfl_xor(bi, s);
            if (ov > bv || (ov == bv && oi < bi)) { bv = ov; bi = oi; }
        }
        chosen[it] = bi;
        // mask the winner in whichever lane owns it
#pragma unroll
        for (int k = 0; k < 16; ++k)
            if (eidx[k] == bi) vals[k] = -FLT_MAX;
    }

    if (lane < NTOP) idx_out[row * NTOP + lane] = chosen[lane];
}

// Stage 2: one block per output row b. Histogram the 5120 contributing indices
// (all b2, t in [64b, 64b+64), n in [0,5)) into LDS, then convolve with the
// truncated Gaussian.
__global__ __launch_bounds__(256) void conv_kernel(const int* __restrict__ idx_in,
                                                   float* __restrict__ out) {
    const int b   = blockIdx.x;   // 0..15
    const int tid = threadIdx.x;  // 0..255

    __shared__ float hist[D_DIM + 2 * RAD];
    __shared__ float w[2 * RAD + 1];

    for (int i = tid; i < D_DIM + 2 * RAD; i += 256) hist[i] = 0.0f;
    if (tid < 2 * RAD + 1) {
        int k = tid - RAD;
        w[tid] = NORM_C * expf(-0.125f * (float)(k * k));
    }
    __syncthreads();

    // gather: chunk b2 is 64*5=320 contiguous ints at (b2*T_DIM + 64*b)*NTOP
    for (int i = tid; i < B_DIM * 320; i += 256) {
        int b2 = i / 320;
        int r  = i % 320;
        int pos = idx_in[(b2 * T_DIM + 64 * b) * NTOP + r];
        atomicAdd(&hist[pos + RAD], 1.0f);   // LDS float atomic; counts exact (< 2^24)
    }
    __syncthreads();

    // out[b,d] = sum_{k=0..2R} hist[d+k] * w[k]   (d = tid + 256*q)
    float acc[4] = {0.f, 0.f, 0.f, 0.f};
    for (int k = 0; k <= 2 * RAD; ++k) {
        float wk = w[k];
#pragma unroll
        for (int q = 0; q < 4; ++q)
            acc[q] += hist[tid + 256 * q + k] * wk;
    }
#pragma unroll
    for (int q = 0; q < 4; ++q)
        out[(size_t)b * D_DIM + tid + 256 * q] = acc[q];
}

extern "C" void kernel_launch(void* const* d_in, const int* in_sizes, int n_in,
                              void* d_out, int out_size, void* d_ws, size_t ws_size,
                              hipStream_t stream) {
    const float* in  = (const float*)d_in[0];
    float*       out = (float*)d_out;
    int*         idx = (int*)d_ws;   // 16384*5 ints = 320 KB

    // Stage 1: 16384 rows, one wave each -> 4096 blocks of 256 (4 waves/block)
    topk5_kernel<<<(B_DIM * T_DIM) / 4, 256, 0, stream>>>(in, idx);
    // Stage 2: one block per output row
    conv_kernel<<<B_DIM, 256, 0, stream>>>(idx, out);
}

// Round 2
// 94.559 us; speedup vs baseline: 1.1156x; 1.1156x over previous
//
#include <hip/hip_runtime.h>
#include <float.h>

#define D_DIM 1024
#define T_DIM 1024
#define B_DIM 16
#define NTOP 5
#define RAD 32              // exp(-k^2/8) == 0.0f in fp32 for |k| >= 29; 32 is safely exact
#define NORM_C 0.19947114f  // np.float32(1/(2*sqrt(2*pi)))
#define THRESH 2.0f         // 5th order stat of 1024 N(0,1) ~ 2.6; P(<5 qualifiers) ~ 3e-7/row
#define CAP 64              // max candidates/row handled on fast path (mean ~23)

// Stage 1: one wave per row. Threshold-filter to ~23 candidates (all positive
// -> raw float bits are a monotone u32 key), compact to wave-private LDS via
// ballot/mbcnt, then all-pairs rank over c<=64 candidates. Exact tie-break
// (lower index wins) via ~idx packed in the low 32 bits of the u64 key.
// Wave-uniform fallback to the full 5-round butterfly when c<5 or c>CAP.
__global__ __launch_bounds__(256) void topk5_kernel(const float* __restrict__ in,
                                                    int* __restrict__ idx_out) {
    const int wave = threadIdx.x >> 6;
    const int lane = threadIdx.x & 63;
    const int row  = blockIdx.x * 4 + wave;   // 0..16383

    const float4* row4 = (const float4*)(in + (size_t)row * D_DIM);

    float vv[16];
#pragma unroll
    for (int j = 0; j < 4; ++j) {
        float4 v = row4[lane + 64 * j];       // coalesced 16B/lane
        vv[4 * j + 0] = v.x; vv[4 * j + 1] = v.y;
        vv[4 * j + 2] = v.z; vv[4 * j + 3] = v.w;
    }

    __shared__ unsigned long long cand[4][CAP];

    // --- filter + wave compaction ---
    unsigned int base = 0;
#pragma unroll
    for (int k = 0; k < 16; ++k) {
        const int j = k >> 2, c4 = k & 3;
        bool p = vv[k] > THRESH;
        unsigned long long m = __ballot(p);
        if (p) {
            unsigned int off = base +
                __builtin_amdgcn_mbcnt_hi((unsigned int)(m >> 32),
                    __builtin_amdgcn_mbcnt_lo((unsigned int)m, 0));
            unsigned int e = 4u * (lane + 64 * j) + c4;
            unsigned long long key =
                ((unsigned long long)__float_as_uint(vv[k]) << 32) | (unsigned int)~e;
            if (off < CAP) cand[wave][off] = key;
        }
        base += (unsigned int)__popcll(m);
    }
    const int c = (int)base;
    __threadfence_block();   // order LDS writes before wave-local reads

    if (c >= NTOP && c <= CAP) {
        // --- fast path: all-pairs rank among c candidates ---
        unsigned long long mykey = (lane < c) ? cand[wave][lane] : 0ULL;
        int rank = 0;
        for (int i = 0; i < c; ++i) {
            unsigned long long bk = __shfl(mykey, i);
            rank += (bk > mykey) ? 1 : 0;
        }
        if (lane < c && rank < NTOP) {
            unsigned int e = ~(unsigned int)mykey;
            idx_out[row * NTOP + rank] = (int)e;
        }
    } else {
        // --- fallback: exact 5-round masked butterfly (round-1 code) ---
        int eidx[16];
#pragma unroll
        for (int k = 0; k < 16; ++k) eidx[k] = 4 * (lane + 64 * (k >> 2)) + (k & 3);
        int chosen[NTOP];
#pragma unroll
        for (int it = 0; it < NTOP; ++it) {
            float bv = -FLT_MAX; int bi = 0x7fffffff;
#pragma unroll
            for (int k = 0; k < 16; ++k)
                if (vv[k] > bv) { bv = vv[k]; bi = eidx[k]; }
#pragma unroll
            for (int s = 1; s < 64; s <<= 1) {
                float ov = __shfl_xor(bv, s);
                int   oi = __shfl_xor(bi, s);
                if (ov > bv || (ov == bv && oi < bi)) { bv = ov; bi = oi; }
            }
            chosen[it] = bi;
#pragma unroll
            for (int k = 0; k < 16; ++k)
                if (eidx[k] == bi) vv[k] = -FLT_MAX;
        }
        if (lane < NTOP) idx_out[row * NTOP + lane] = chosen[lane];
    }
}

// Stage 2: 4 blocks per output row b; each block covers 256 outputs with a
// 320-bin windowed LDS histogram, then convolves with the truncated Gaussian.
__global__ __launch_bounds__(256) void conv_kernel(const int* __restrict__ idx_in,
                                                   float* __restrict__ out) {
    const int b   = blockIdx.x >> 2;          // 0..15
    const int d0  = (blockIdx.x & 3) * 256;   // output slice start
    const int tid = threadIdx.x;

    __shared__ float hist[256 + 2 * RAD];     // bin 0 <-> pos = d0 - RAD
    __shared__ float w[2 * RAD + 1];

    hist[tid] = 0.0f;
    if (tid < 2 * RAD) hist[256 + tid] = 0.0f;
    if (tid < 2 * RAD + 1) {
        int k = tid - RAD;
        w[tid] = NORM_C * expf(-0.125f * (float)(k * k));
    }
    __syncthreads();

    // gather: indices for row b are at (b2*T_DIM + 64*b)*NTOP + r, r in [0,320)
    // per b2; 320 ints are int4-aligned (320 = 80 * int4).
    for (int i = tid; i < B_DIM * 80; i += 256) {
        int b2 = i / 80;
        int r4 = i % 80;
        const int4* p = (const int4*)(idx_in + ((size_t)b2 * T_DIM + 64 * b) * NTOP);
        int4 pos = p[r4];
        unsigned int l0 = (unsigned int)(pos.x - d0 + RAD);
        unsigned int l1 = (unsigned int)(pos.y - d0 + RAD);
        unsigned int l2 = (unsigned int)(pos.z - d0 + RAD);
        unsigned int l3 = (unsigned int)(pos.w - d0 + RAD);
        if (l0 < 256 + 2 * RAD) atomicAdd(&hist[l0], 1.0f);
        if (l1 < 256 + 2 * RAD) atomicAdd(&hist[l1], 1.0f);
        if (l2 < 256 + 2 * RAD) atomicAdd(&hist[l2], 1.0f);
        if (l3 < 256 + 2 * RAD) atomicAdd(&hist[l3], 1.0f);
    }
    __syncthreads();

    // out[b, d0+tid] = sum_k hist[tid+k] * w[k]  (diff = RAD - k, exact)
    float acc = 0.0f;
    for (int k = 0; k <= 2 * RAD; ++k)
        acc += hist[tid + k] * w[k];
    out[(size_t)b * D_DIM + d0 + tid] = acc;
}

extern "C" void kernel_launch(void* const* d_in, const int* in_sizes, int n_in,
                              void* d_out, int out_size, void* d_ws, size_t ws_size,
                              hipStream_t stream) {
    const float* in  = (const float*)d_in[0];
    float*       out = (float*)d_out;
    int*         idx = (int*)d_ws;   // 16384*5 ints = 320 KB

    topk5_kernel<<<(B_DIM * T_DIM) / 4, 256, 0, stream>>>(in, idx);
    conv_kernel<<<B_DIM * 4, 256, 0, stream>>>(idx, out);
}